// Round 6
// baseline (12373.355 us; speedup 1.0000x reference)
//
#include <hip/hip_runtime.h>
#include <hip/hip_bf16.h>
#include <hip/hip_fp16.h>
#include <stdint.h>

#define BB 64
#define TT 512
#define II 256
#define HH 1024
#define G4 4096
#define SENT 0x7C00u            // fp16 +inf: |h|<=1 so data NEVER equals this

typedef unsigned short u16;
typedef unsigned long long u64;
typedef __attribute__((ext_vector_type(8))) _Float16 h8;
typedef __attribute__((ext_vector_type(4))) float f32x4;

__device__ __forceinline__ u16 f2h(float x){
  _Float16 h = (_Float16)x;
  return __builtin_bit_cast(u16, h);
}
__device__ __forceinline__ float sigm(float x){ return 1.0f/(1.0f + __expf(-x)); }
__device__ __forceinline__ float tanh_f(float x){ return 1.0f - 2.0f/(1.0f + __expf(2.0f*x)); }

__device__ __forceinline__ u64 aload8(const u16* p){
  return __hip_atomic_load((const u64*)p, __ATOMIC_RELAXED, __HIP_MEMORY_SCOPE_AGENT);
}
// one check per 4B producer granule (halfwords 0 and 2 of the 8B unit)
__device__ __forceinline__ int stale(u64 v){
  return ((v & 0xffffull) == SENT) || (((v >> 32) & 0xffffull) == SENT);
}
__device__ __forceinline__ h8 mk16(u64 lo, u64 hi){
  union { u64 v[2]; h8 h; } u; u.v[0] = lo; u.v[1] = hi; return u.h;
}

// ---------------- prep kernels ----------------
__global__ void bias_comb_kernel(const float* __restrict__ a, const float* __restrict__ b,
                                 float* __restrict__ o, int n){
  int i = blockIdx.x*blockDim.x + threadIdx.x;
  if (i < n) o[i] = a[i] + b[i];
}

// h rings init: slot 0 = fp16 zeros (h[-1]); slots 1..15 = sentinel
__global__ void hinit_kernel(unsigned* __restrict__ h0, unsigned* __restrict__ h1){
  int i = blockIdx.x*blockDim.x + threadIdx.x;     // u32 index, 1<<19 per buf
  unsigned slot = ((unsigned)i) >> 15;             // 32768 u32 per slot
  unsigned v = (slot == 0) ? 0u : (SENT | (SENT << 16));
  h0[i] = v;
  h1[i] = v;
}

// x: [B][T][I] fp32 -> xb: [(t*B+b)][I] fp16
__global__ void xconv_kernel(const float* __restrict__ x, u16* __restrict__ xb){
  int m = blockIdx.x;            // t*BB + b
  int t = m >> 6, b = m & 63;
  const float4* src = (const float4*)(x + ((size_t)b*TT + t)*II);
  float4 v = src[threadIdx.x];   // 64 threads * 4 = 256 = II
  ushort4 o; o.x=f2h(v.x); o.y=f2h(v.y); o.z=f2h(v.z); o.w=f2h(v.w);
  ((ushort4*)(xb + (size_t)m*II))[threadIdx.x] = o;
}

// Concat-K weight swizzle into MFMA B-frag order (fp32 -> fp16).
__global__ void wswz_kernel(const float* __restrict__ Wa, int Ka,
                            const float* __restrict__ Wb, int Kb,
                            u16* __restrict__ dst, int KS){
  int s8 = blockIdx.x*blockDim.x + threadIdx.x;
  int lane = s8 & 63;
  int f    = (s8 >> 6) & 1;
  int rest = s8 >> 7;
  int ks   = rest % KS;
  int jg8  = rest / KS;
  if (jg8 >= 128) return;
  int id = lane & 15, quad = lane >> 4;
  int g = f*2 + (id >> 3);
  int n = g*HH + jg8*8 + (id & 7);
  int k = ks*32 + quad*8;
  const float* src = (k < Ka) ? (Wa + (size_t)n*Ka + k) : (Wb + (size_t)n*Kb + (k - Ka));
  float4 v0 = ((const float4*)src)[0];
  float4 v1 = ((const float4*)src)[1];
  ushort4 o0; o0.x=f2h(v0.x); o0.y=f2h(v0.y); o0.z=f2h(v0.z); o0.w=f2h(v0.w);
  ushort4 o1; o1.x=f2h(v1.x); o1.y=f2h(v1.y); o1.z=f2h(v1.z); o1.w=f2h(v1.w);
  u16* d = dst + (size_t)s8*8;
  ((ushort4*)d)[0] = o0;
  ((ushort4*)d)[1] = o1;
}

// bulk-issue NL k-steps x 4 M-tiles of A-frags (pipelined), validate each 8B
// unit against the sentinel (retry only stale units), then MFMA.
#define STAGE_MFMA(BASE, NL, HSRC, KOFS) do {                                   \
  u64 st[(NL)*8];                                                               \
  _Pragma("unroll")                                                             \
  for (int l4 = 0; l4 < (NL); ++l4){                                            \
    _Pragma("unroll")                                                           \
    for (int mt = 0; mt < 4; ++mt){                                             \
      const u16* pp = (HSRC) + ((size_t)(mt*16 + id) << 10)                     \
                      + ((KOFS) + ((BASE)+l4)*32 + quad*8);                     \
      st[(l4*4+mt)*2  ] = aload8(pp);                                           \
      st[(l4*4+mt)*2+1] = aload8(pp + 4);                                       \
    }                                                                           \
  }                                                                             \
  _Pragma("unroll")                                                             \
  for (int i = 0; i < (NL)*8; ++i){                                             \
    if (stale(st[i])){                                                          \
      const u16* pp = (HSRC) + ((size_t)(((i>>1)&3)*16 + id) << 10)             \
                      + ((KOFS) + ((BASE)+(i>>3))*32 + quad*8 + (i&1)*4);       \
      do { __builtin_amdgcn_s_sleep(1); st[i] = aload8(pp); } while (stale(st[i])); \
    }                                                                           \
  }                                                                             \
  _Pragma("unroll")                                                             \
  for (int l4 = 0; l4 < (NL); ++l4){                                            \
    _Pragma("unroll")                                                           \
    for (int mt = 0; mt < 4; ++mt){                                             \
      h8 a = mk16(st[(l4*4+mt)*2], st[(l4*4+mt)*2+1]);                          \
      a0[mt] = __builtin_amdgcn_mfma_f32_16x16x32_f16(a, w0[(BASE)+l4], a0[mt], 0,0,0); \
      a1[mt] = __builtin_amdgcn_mfma_f32_16x16x32_f16(a, w1[(BASE)+l4], a1[mt], 0,0,0); \
    }                                                                           \
  }                                                                             \
} while(0)

// ---------------- fused 2-layer persistent LSTM, data-is-the-flag ----------------
// 256 blocks x 256 threads. blocks 0..127: layer0; 128..255: layer1.
// K-split across waves, weights preloaded in VGPRs (round-5 win kept).
// NEW protocol: h rings are 16 slots; h data itself is the readiness flag.
//   producer (epoch t): write h[t] -> slot (t+1)&15 (agent atomics, 4B granules);
//                       pre-reset slot (t+9)&15 to fp16-inf sentinel.
//   consumer: bulk-load its A-frags, validate each 8B unit (halfwords 0/2 !=
//             0x7C00), retry only stale units. NO stamp waits, NO drains on the
//             critical path -> ~1 fabric RT per epoch handoff.
// Reset safety: slot (t+9)&15 holds h[t-8]; same-layer peers are >= t-1 (they
// consumed our h[t-1]); cross-layer (y0) guarded by lazy credit L1 >= t-7.
// Same-address reset->write ordering is per-address coherence + the epoch-end
// __syncthreads (vmcnt drain) 8 epochs earlier.
__launch_bounds__(256, 1)
__global__ void lstm_fused_kernel(const u16* __restrict__ xb,
                                  const u16* __restrict__ Wsw0,
                                  const u16* __restrict__ Wsw1,
                                  const float* __restrict__ bias0,
                                  const float* __restrict__ bias1,
                                  u16* __restrict__ h0buf,   // 16 slots [64][1024] fp16
                                  u16* __restrict__ h1buf,   // 16 slots
                                  float* __restrict__ hfin,  // [2][64][1024] fp32
                                  int* __restrict__ stamp1){ // 128 slots, stride 32 ints
  __shared__ float Gs[4][32][68];    // [wave][gate-row 2f x 16id][batch 64+pad]
  const int blk = blockIdx.x;
  const int layer = blk >> 7;
  const int jg = blk & 127;
  const int tid = threadIdx.x, wave = tid >> 6, lane = tid & 63;
  const int id = lane & 15, quad = lane >> 4;
  const int KS = layer ? 64 : 40;
  const int KSW = layer ? 16 : 10;
  const u16* Wblk = (layer ? Wsw1 : Wsw0) + (size_t)jg * KS * 1024;
  const int cb = tid >> 2, jq = tid & 3;  // cell phase: batch cb, j-pair jq
  const int j0 = jg * 8;
  const float* Bp = layer ? bias1 : bias0;
  float bs[4][2];
  #pragma unroll
  for (int g = 0; g < 4; ++g)
    #pragma unroll
    for (int jj = 0; jj < 2; ++jj)
      bs[g][jj] = Bp[g*HH + j0 + jq*2 + jj];
  float c2[2] = {0.f, 0.f};
  const int wb = wave * KSW;

  if (layer == 0){
    // ---- preload weight fragment: 10 steps x 2 frags = 80 VGPR ----
    h8 w0[10], w1[10];
    #pragma unroll
    for (int l = 0; l < 10; ++l){
      const u16* wl = Wblk + (size_t)(wb + l)*1024 + lane*8;
      w0[l] = *(const h8*)(wl);
      w1[l] = *(const h8*)(wl + 512);
    }
    // wave w covers k [w*320, w*320+320): wave0 = 256 x-cols + 64 h; waves1-3 all h
    const int hko = wb*32 - 256;               // h-offset of l=0 (negative only for wave0)
    int credit = 0;
    for (int t = 0; t < TT; ++t){
      const u16* hA = h0buf + ((size_t)(t & 15) << 16);        // h0[t-1]
      u16* hout     = h0buf + ((size_t)((t + 1) & 15) << 16);  // h0[t]
      u16* hrst     = h0buf + ((size_t)((t + 9) & 15) << 16);  // pre-reset target
      f32x4 a0[4] = {}, a1[4] = {};
      if (wave == 0){
        // x-part: h-independent (plain cached loads)
        #pragma unroll
        for (int l = 0; l < 8; ++l){
          #pragma unroll
          for (int mt = 0; mt < 4; ++mt){
            int abm = mt*16 + id;
            h8 a = *(const h8*)(xb + (((size_t)t*64 + abm) << 8) + l*32 + quad*8);
            a0[mt] = __builtin_amdgcn_mfma_f32_16x16x32_f16(a, w0[l], a0[mt], 0,0,0);
            a1[mt] = __builtin_amdgcn_mfma_f32_16x16x32_f16(a, w1[l], a1[mt], 0,0,0);
          }
        }
        // lazy credit: before this epoch's reset of y0[t-8]'s slot, L1 >= t-7.
        while (credit < t - 7){
          int sa = __hip_atomic_load(stamp1 + lane*32,      __ATOMIC_RELAXED, __HIP_MEMORY_SCOPE_AGENT);
          int sb = __hip_atomic_load(stamp1 + (64+lane)*32, __ATOMIC_RELAXED, __HIP_MEMORY_SCOPE_AGENT);
          int s = sa < sb ? sa : sb;
          #pragma unroll
          for (int off = 32; off; off >>= 1){
            int s2 = __shfl_xor(s, off);
            s = s < s2 ? s : s2;
          }
          credit = s;
          if (credit < t - 7) __builtin_amdgcn_s_sleep(8);
        }
        STAGE_MFMA(8, 2, hA, hko);
      } else {
        STAGE_MFMA(0, 5, hA, hko);
        STAGE_MFMA(5, 5, hA, hko);
      }
      // ---- exchange: D lane(id,quad) reg r -> batch mt*16+quad*4+r, row f*16+id ----
      #pragma unroll
      for (int mt = 0; mt < 4; ++mt){
        *(f32x4*)&Gs[wave][id][mt*16 + quad*4]      = a0[mt];
        *(f32x4*)&Gs[wave][16 + id][mt*16 + quad*4] = a1[mt];
      }
      __syncthreads();   // Gs ready; also gates stores below on wave0's credit
      // ---- cell phase: 2 cells (batch cb, j = j0 + jq*2 + jj) ----
      ushort2 hb; float2 hf;
      #pragma unroll
      for (int jj = 0; jj < 2; ++jj){
        int jl = jq*2 + jj;
        float p[4];
        #pragma unroll
        for (int g = 0; g < 4; ++g){
          int e = (g >> 1)*16 + (g & 1)*8 + jl;
          p[g] = Gs[0][e][cb] + Gs[1][e][cb] + Gs[2][e][cb] + Gs[3][e][cb] + bs[g][jj];
        }
        float iv = sigm(p[0]), fv = sigm(p[1]), gv = tanh_f(p[2]), ov = sigm(p[3]);
        float c = fv*c2[jj] + iv*gv;
        c2[jj] = c;
        float h = ov * tanh_f(c);
        (&hf.x)[jj] = h;
        ((u16*)&hb)[jj] = f2h(h);
      }
      union { ushort2 s; unsigned int v; } pk; pk.s = hb;
      __hip_atomic_store((unsigned int*)&hout[(size_t)cb*HH + j0 + jq*2],
                         pk.v, __ATOMIC_RELAXED, __HIP_MEMORY_SCOPE_AGENT);
      __hip_atomic_store((unsigned int*)&hrst[(size_t)cb*HH + j0 + jq*2],
                         SENT | (SENT << 16), __ATOMIC_RELAXED, __HIP_MEMORY_SCOPE_AGENT);
      if (t == TT - 1)
        *(float2*)&hfin[(size_t)cb*HH + j0 + jq*2] = hf;
      __syncthreads();   // protects Gs reuse; drains stores (acks) each epoch
    }
  } else {
    // ---- preload weight fragment: 16 steps x 2 frags = 128 VGPR ----
    h8 w0[16], w1[16];
    #pragma unroll
    for (int l = 0; l < 16; ++l){
      const u16* wl = Wblk + (size_t)(wb + l)*1024 + lane*8;
      w0[l] = *(const h8*)(wl);
      w1[l] = *(const h8*)(wl + 512);
    }
    // wave w covers k [w*512, (w+1)*512): waves 0-1 read y0, waves 2-3 read h1
    const int koff = (wave & 1) * 512;
    for (int t = 0; t < TT; ++t){
      const u16* y0  = h0buf + ((size_t)((t + 1) & 15) << 16); // y0[t] = h0[t]
      const u16* hAs = h1buf + ((size_t)(t & 15) << 16);       // h1[t-1]
      u16* hout      = h1buf + ((size_t)((t + 1) & 15) << 16); // h1[t]
      u16* hrst      = h1buf + ((size_t)((t + 9) & 15) << 16);
      const u16* hsrc = (wave < 2) ? y0 : hAs;
      f32x4 a0[4] = {}, a1[4] = {};
      STAGE_MFMA(0, 8, hsrc, koff);
      STAGE_MFMA(8, 8, hsrc, koff);
      #pragma unroll
      for (int mt = 0; mt < 4; ++mt){
        *(f32x4*)&Gs[wave][id][mt*16 + quad*4]      = a0[mt];
        *(f32x4*)&Gs[wave][16 + id][mt*16 + quad*4] = a1[mt];
      }
      __syncthreads();
      ushort2 hb; float2 hf;
      #pragma unroll
      for (int jj = 0; jj < 2; ++jj){
        int jl = jq*2 + jj;
        float p[4];
        #pragma unroll
        for (int g = 0; g < 4; ++g){
          int e = (g >> 1)*16 + (g & 1)*8 + jl;
          p[g] = Gs[0][e][cb] + Gs[1][e][cb] + Gs[2][e][cb] + Gs[3][e][cb] + bs[g][jj];
        }
        float iv = sigm(p[0]), fv = sigm(p[1]), gv = tanh_f(p[2]), ov = sigm(p[3]);
        float c = fv*c2[jj] + iv*gv;
        c2[jj] = c;
        float h = ov * tanh_f(c);
        (&hf.x)[jj] = h;
        ((u16*)&hb)[jj] = f2h(h);
      }
      union { ushort2 s; unsigned int v; } pk; pk.s = hb;
      __hip_atomic_store((unsigned int*)&hout[(size_t)cb*HH + j0 + jq*2],
                         pk.v, __ATOMIC_RELAXED, __HIP_MEMORY_SCOPE_AGENT);
      __hip_atomic_store((unsigned int*)&hrst[(size_t)cb*HH + j0 + jq*2],
                         SENT | (SENT << 16), __ATOMIC_RELAXED, __HIP_MEMORY_SCOPE_AGENT);
      if (t == TT - 1)
        *(float2*)&hfin[(size_t)(BB*HH) + (size_t)cb*HH + j0 + jq*2] = hf;
      // progress stamp for L0's credit: all reads of y0[t] completed before the
      // syncthreads above; visibility lag only makes L0 more conservative.
      if (tid == 0)
        __hip_atomic_store(stamp1 + jg*32, t + 1, __ATOMIC_RELAXED, __HIP_MEMORY_SCOPE_AGENT);
      __syncthreads();
    }
  }
}

// ---------------- FC head ----------------
__global__ void fc_kernel(const float* __restrict__ hfin, const float* __restrict__ fcw,
                          const float* __restrict__ fcb, float* __restrict__ out){
  int row = blockIdx.x;          // 0..127  (0..63 layer0 hT, 64..127 layer1 hT)
  int lane = threadIdx.x;        // 64
  const float* h = hfin + (size_t)row*HH;
  float a0 = 0.f, a1 = 0.f;
  for (int j = lane; j < HH; j += 64){
    float v = h[j]; v = v > 0.f ? v : 0.f;
    a0 += v * fcw[j];
    a1 += v * fcw[HH + j];
  }
  for (int off = 32; off; off >>= 1){ a0 += __shfl_down(a0, off); a1 += __shfl_down(a1, off); }
  if (lane == 0){
    out[row*2 + 0] = 1.f/(1.f + __expf(-(a0 + fcb[0])));
    out[row*2 + 1] = 1.f/(1.f + __expf(-(a1 + fcb[1])));
  }
}

// ---------------- launch ----------------
extern "C" void kernel_launch(void* const* d_in, const int* in_sizes, int n_in,
                              void* d_out, int out_size, void* d_ws, size_t ws_size,
                              hipStream_t stream){
  (void)in_sizes; (void)n_in; (void)out_size; (void)ws_size;
  const float* x    = (const float*)d_in[0];
  const float* Wih0 = (const float*)d_in[1];
  const float* Whh0 = (const float*)d_in[2];
  const float* bih0 = (const float*)d_in[3];
  const float* bhh0 = (const float*)d_in[4];
  const float* Wih1 = (const float*)d_in[5];
  const float* Whh1 = (const float*)d_in[6];
  const float* bih1 = (const float*)d_in[7];
  const float* bhh1 = (const float*)d_in[8];
  const float* fcw  = (const float*)d_in[9];
  const float* fcb  = (const float*)d_in[10];

  char* w = (char*)d_ws;
  size_t off = 0;
  auto take = [&](size_t bytes)->char*{
    char* p = w + off; off += (bytes + 255) & ~(size_t)255; return p;
  };
  u16*   xb    = (u16*)  take((size_t)TT*BB*II*2);       // 16 MB
  u16*   wsw0  = (u16*)  take((size_t)G4*1280*2);        // 10 MB  (K=256+1024)
  u16*   wsw1  = (u16*)  take((size_t)G4*2048*2);        // 16 MB  (K=1024+1024)
  float* bias0 = (float*)take(G4*4);
  float* bias1 = (float*)take(G4*4);
  u16*   h0buf = (u16*)  take(16*(size_t)BB*HH*2);       // 2 MB ring (16 slots)
  u16*   h1buf = (u16*)  take(16*(size_t)BB*HH*2);
  float* hfin  = (float*)take(2*(size_t)BB*HH*4);        // 512 KB
  int*   stamp1= (int*)  take(128*128);                  // 128 slots x 128B

  hipMemsetAsync(stamp1, 0, 128*128, stream);

  bias_comb_kernel<<<16, 256, 0, stream>>>(bih0, bhh0, bias0, G4);
  bias_comb_kernel<<<16, 256, 0, stream>>>(bih1, bhh1, bias1, G4);
  hinit_kernel<<<2048, 256, 0, stream>>>((unsigned*)h0buf, (unsigned*)h1buf);
  xconv_kernel<<<TT*BB, 64, 0, stream>>>(x, xb);
  wswz_kernel<<<2560, 256, 0, stream>>>(Wih0, II, Whh0, HH, wsw0, 40);
  wswz_kernel<<<4096, 256, 0, stream>>>(Wih1, HH, Whh1, HH, wsw1, 64);

  lstm_fused_kernel<<<256, 256, 0, stream>>>(xb, wsw0, wsw1, bias0, bias1,
                                             h0buf, h1buf, hfin, stamp1);
  fc_kernel<<<2*BB, 64, 0, stream>>>(hfin, fcw, fcb, (float*)d_out);
}

// Round 7
// 9150.550 us; speedup vs baseline: 1.3522x; 1.3522x over previous
//
#include <hip/hip_runtime.h>
#include <hip/hip_bf16.h>
#include <hip/hip_fp16.h>
#include <stdint.h>

#define BB 64
#define TT 512
#define II 256
#define HH 1024
#define G4 4096

typedef unsigned short u16;
typedef unsigned long long u64;
typedef __attribute__((ext_vector_type(8))) _Float16 h8;
typedef __attribute__((ext_vector_type(4))) float f32x4;

__device__ __forceinline__ u16 f2h(float x){
  _Float16 h = (_Float16)x;
  return __builtin_bit_cast(u16, h);
}
__device__ __forceinline__ float sigm(float x){ return 1.0f/(1.0f + __expf(-x)); }
__device__ __forceinline__ float tanh_f(float x){ return 1.0f - 2.0f/(1.0f + __expf(2.0f*x)); }

// agent-scope (cross-XCD coherent) 16B load as two relaxed 8B atomics
__device__ __forceinline__ h8 aload16(const u16* p){
  union { u64 v[2]; h8 h; } u;
  const u64* q = (const u64*)p;
  u.v[0] = __hip_atomic_load(q,     __ATOMIC_RELAXED, __HIP_MEMORY_SCOPE_AGENT);
  u.v[1] = __hip_atomic_load(q + 1, __ATOMIC_RELAXED, __HIP_MEMORY_SCOPE_AGENT);
  return u.h;
}
// min of a 4-int per-wave stamp quad (two 8B relaxed agent loads)
__device__ __forceinline__ int min4q(const int* q){
  u64 a = __hip_atomic_load((const u64*)q,       __ATOMIC_RELAXED, __HIP_MEMORY_SCOPE_AGENT);
  u64 b = __hip_atomic_load((const u64*)(q + 2), __ATOMIC_RELAXED, __HIP_MEMORY_SCOPE_AGENT);
  int m0 = (int)(unsigned)(a & 0xffffffffull), m1 = (int)(unsigned)(a >> 32);
  int m2 = (int)(unsigned)(b & 0xffffffffull), m3 = (int)(unsigned)(b >> 32);
  int m = m0 < m1 ? m0 : m1;
  int n = m2 < m3 ? m2 : m3;
  return m < n ? m : n;
}

// ---------------- prep kernels ----------------
__global__ void bias_comb_kernel(const float* __restrict__ a, const float* __restrict__ b,
                                 float* __restrict__ o, int n){
  int i = blockIdx.x*blockDim.x + threadIdx.x;
  if (i < n) o[i] = a[i] + b[i];
}

// x: [B][T][I] fp32 -> xb: [(t*B+b)][I] fp16
__global__ void xconv_kernel(const float* __restrict__ x, u16* __restrict__ xb){
  int m = blockIdx.x;            // t*BB + b
  int t = m >> 6, b = m & 63;
  const float4* src = (const float4*)(x + ((size_t)b*TT + t)*II);
  float4 v = src[threadIdx.x];   // 64 threads * 4 = 256 = II
  ushort4 o; o.x=f2h(v.x); o.y=f2h(v.y); o.z=f2h(v.z); o.w=f2h(v.w);
  ((ushort4*)(xb + (size_t)m*II))[threadIdx.x] = o;
}

// Concat-K weight swizzle into MFMA B-frag order (fp32 -> fp16).
__global__ void wswz_kernel(const float* __restrict__ Wa, int Ka,
                            const float* __restrict__ Wb, int Kb,
                            u16* __restrict__ dst, int KS){
  int s8 = blockIdx.x*blockDim.x + threadIdx.x;
  int lane = s8 & 63;
  int f    = (s8 >> 6) & 1;
  int rest = s8 >> 7;
  int ks   = rest % KS;
  int jg8  = rest / KS;
  if (jg8 >= 128) return;
  int id = lane & 15, quad = lane >> 4;
  int g = f*2 + (id >> 3);
  int n = g*HH + jg8*8 + (id & 7);
  int k = ks*32 + quad*8;
  const float* src = (k < Ka) ? (Wa + (size_t)n*Ka + k) : (Wb + (size_t)n*Kb + (k - Ka));
  float4 v0 = ((const float4*)src)[0];
  float4 v1 = ((const float4*)src)[1];
  ushort4 o0; o0.x=f2h(v0.x); o0.y=f2h(v0.y); o0.z=f2h(v0.z); o0.w=f2h(v0.w);
  ushort4 o1; o1.x=f2h(v1.x); o1.y=f2h(v1.y); o1.z=f2h(v1.z); o1.w=f2h(v1.w);
  u16* d = dst + (size_t)s8*8;
  ((ushort4*)d)[0] = o0;
  ((ushort4*)d)[1] = o1;
}

// ---------------- fused 2-layer persistent LSTM, wave-decoupled stamps ----------------
// 256 blocks x 256 threads. blocks 0..127: layer0; 128..255: layer1.
// K-split across waves, weights preloaded in VGPRs (round-5 win kept).
// Sync refinements vs round-5 (protocol family unchanged: stamps + 8-slot rings):
//  * PER-WAVE stamps: stamp quad [4 ints] per block. Producer wave drains ONLY its
//    own stores (wave-local s_waitcnt vmcnt(0)) then stamps: no epoch-end barrier.
//    Sound because each consumer 8B unit (one batch row) is written by exactly one
//    producer wave (batch ab -> wave ab>>4).
//  * WAVE-LOCAL waits: each consumer wave polls only the producer blocks covering
//    its K-slice (<=64, one per lane, quad-min >= needed), no barrier before GEMM.
//  * Gs parity double-buffer -> exactly ONE __syncthreads per epoch (exchange).
//  * L0 x-work spread over all 4 waves (2 x-ksteps each, pre-wait), h-ksteps 8/wave.
__launch_bounds__(256, 1)
__global__ void lstm_fused_kernel(const u16* __restrict__ xb,
                                  const u16* __restrict__ Wsw0,
                                  const u16* __restrict__ Wsw1,
                                  const float* __restrict__ bias0,
                                  const float* __restrict__ bias1,
                                  u16* __restrict__ h0buf,   // 8 slots [64][1024] fp16
                                  u16* __restrict__ h1buf,   // 8 slots
                                  float* __restrict__ hfin,  // [2][64][1024] fp32
                                  int* __restrict__ stamp0,  // 128 quads, stride 32 ints
                                  int* __restrict__ stamp1){ // 128 quads, stride 32 ints
  __shared__ float Gs[2][4][32][68];   // [parity][wave][gate-row 2f x 16id][batch 64+pad]
  const int blk = blockIdx.x;
  const int layer = blk >> 7;
  const int jg = blk & 127;
  const int tid = threadIdx.x, wave = tid >> 6, lane = tid & 63;
  const int id = lane & 15, quad = lane >> 4;
  const int KS = layer ? 64 : 40;
  const u16* Wblk = (layer ? Wsw1 : Wsw0) + (size_t)jg * KS * 1024;
  const int cb = tid >> 2, jq = tid & 3;  // cell phase: batch cb, j-pair jq
  const int j0 = jg * 8;
  const float* Bp = layer ? bias1 : bias0;
  float bs[4][2];
  #pragma unroll
  for (int g = 0; g < 4; ++g)
    #pragma unroll
    for (int jj = 0; jj < 2; ++jj)
      bs[g][jj] = Bp[g*HH + j0 + jq*2 + jj];
  float c2[2] = {0.f, 0.f};

  if (layer == 0){
    // ---- preload weight fragment: wave w owns x-ksteps {2w,2w+1} + h-ksteps {8+8w..8+8w+7} ----
    h8 w0[10], w1[10];
    #pragma unroll
    for (int i = 0; i < 10; ++i){
      int ks = (i < 2) ? (2*wave + i) : (8 + 8*wave + (i - 2));
      const u16* wl = Wblk + (size_t)ks*1024 + lane*8;
      w0[i] = *(const h8*)(wl);
      w1[i] = *(const h8*)(wl + 512);
    }
    const int* myq = stamp0 + (32*wave + (lane & 31))*32;   // this wave's producer set
    int credit = 0;
    for (int t = 0; t < TT; ++t){
      const u16* hA = h0buf + ((size_t)(t & 7) << 16);        // h0[t-1]
      u16* hout     = h0buf + ((size_t)((t + 1) & 7) << 16);  // h0[t]
      f32x4 a0[4] = {}, a1[4] = {};
      // ---- x-part: h-independent (plain cached loads), overlaps peers' tail ----
      #pragma unroll
      for (int i = 0; i < 2; ++i){
        int xcol = (2*wave + i)*32 + quad*8;
        #pragma unroll
        for (int mt = 0; mt < 4; ++mt){
          int abm = mt*16 + id;
          h8 a = *(const h8*)(xb + (((size_t)t*64 + abm) << 8) + xcol);
          a0[mt] = __builtin_amdgcn_mfma_f32_16x16x32_f16(a, w0[i], a0[mt], 0,0,0);
          a1[mt] = __builtin_amdgcn_mfma_f32_16x16x32_f16(a, w1[i], a1[mt], 0,0,0);
        }
      }
      // ---- lazy anti-overwrite credit (wave0 only): y0[t-8] slot reuse needs L1 >= t-7 ----
      if (wave == 0){
        while (credit < t - 7){
          int s  = min4q(stamp1 + lane*32);
          int s2 = min4q(stamp1 + (64 + lane)*32);
          s = s < s2 ? s : s2;
          #pragma unroll
          for (int off = 32; off; off >>= 1){
            int sx = __shfl_xor(s, off);
            s = s < sx ? s : sx;
          }
          credit = s;
          if (credit < t - 7) __builtin_amdgcn_s_sleep(8);
        }
      }
      // ---- wave-local wait: my 32 producer blocks published h0[t-1] ----
      while (min4q(myq) < t) __builtin_amdgcn_s_sleep(1);
      asm volatile("" ::: "memory");
      // ---- h-part: 8 ksteps, cols [wave*256, wave*256+256) ----
      #pragma unroll
      for (int i = 2; i < 10; ++i){
        int hcol = wave*256 + (i - 2)*32 + quad*8;
        #pragma unroll
        for (int mt = 0; mt < 4; ++mt){
          int abm = mt*16 + id;
          h8 a = aload16(hA + ((size_t)abm << 10) + hcol);
          a0[mt] = __builtin_amdgcn_mfma_f32_16x16x32_f16(a, w0[i], a0[mt], 0,0,0);
          a1[mt] = __builtin_amdgcn_mfma_f32_16x16x32_f16(a, w1[i], a1[mt], 0,0,0);
        }
      }
      // ---- exchange (parity buffer): D lane(id,quad) reg r -> batch mt*16+quad*4+r ----
      #pragma unroll
      for (int mt = 0; mt < 4; ++mt){
        *(f32x4*)&Gs[t & 1][wave][id][mt*16 + quad*4]      = a0[mt];
        *(f32x4*)&Gs[t & 1][wave][16 + id][mt*16 + quad*4] = a1[mt];
      }
      __syncthreads();     // the ONLY barrier this epoch
      // ---- cell phase: 2 cells (batch cb, j = j0 + jq*2 + jj) ----
      ushort2 hb; float2 hf;
      #pragma unroll
      for (int jj = 0; jj < 2; ++jj){
        int jl = jq*2 + jj;
        float p[4];
        #pragma unroll
        for (int g = 0; g < 4; ++g){
          int e = (g >> 1)*16 + (g & 1)*8 + jl;
          p[g] = Gs[t & 1][0][e][cb] + Gs[t & 1][1][e][cb]
               + Gs[t & 1][2][e][cb] + Gs[t & 1][3][e][cb] + bs[g][jj];
        }
        float iv = sigm(p[0]), fv = sigm(p[1]), gv = tanh_f(p[2]), ov = sigm(p[3]);
        float c = fv*c2[jj] + iv*gv;
        c2[jj] = c;
        float h = ov * tanh_f(c);
        (&hf.x)[jj] = h;
        ((u16*)&hb)[jj] = f2h(h);
      }
      union { ushort2 s; unsigned int v; } pk; pk.s = hb;
      __hip_atomic_store((unsigned int*)&hout[(size_t)cb*HH + j0 + jq*2],
                         pk.v, __ATOMIC_RELAXED, __HIP_MEMORY_SCOPE_AGENT);
      if (t == TT - 1)
        *(float2*)&hfin[(size_t)cb*HH + j0 + jq*2] = hf;
      // ---- wave-local drain + per-wave stamp (no barrier) ----
      asm volatile("s_waitcnt vmcnt(0)" ::: "memory");
      if (lane == 0)
        __hip_atomic_store(stamp0 + jg*32 + wave, t + 1, __ATOMIC_RELAXED, __HIP_MEMORY_SCOPE_AGENT);
    }
  } else {
    // ---- preload weight fragment: 16 steps x 2 frags = 128 VGPR ----
    h8 w0[16], w1[16];
    const int wb = wave * 16;
    #pragma unroll
    for (int l = 0; l < 16; ++l){
      const u16* wl = Wblk + (size_t)(wb + l)*1024 + lane*8;
      w0[l] = *(const h8*)(wl);
      w1[l] = *(const h8*)(wl + 512);
    }
    // waves 0-1 read y0 halves (producers = stamp0 blocks 64w..64w+63, need >= t+1);
    // waves 2-3 read h1 halves (producers = stamp1 blocks, need >= t)
    const int koff = (wave & 1) * 512;
    const int* myq = (wave < 2) ? (stamp0 + (64*wave + lane)*32)
                                : (stamp1 + (64*(wave - 2) + lane)*32);
    for (int t = 0; t < TT; ++t){
      const u16* y0  = h0buf + ((size_t)((t + 1) & 7) << 16); // y0[t] = h0[t]
      const u16* hA1 = h1buf + ((size_t)(t & 7) << 16);       // h1[t-1]
      u16* hout      = h1buf + ((size_t)((t + 1) & 7) << 16); // h1[t]
      const u16* hsrc = (wave < 2) ? y0 : hA1;
      const int need  = (wave < 2) ? (t + 1) : t;
      // ---- wave-local wait ----
      while (min4q(myq) < need) __builtin_amdgcn_s_sleep(1);
      asm volatile("" ::: "memory");
      f32x4 a0[4] = {}, a1[4] = {};
      #pragma unroll
      for (int l = 0; l < 16; ++l){
        int col = koff + l*32 + quad*8;
        #pragma unroll
        for (int mt = 0; mt < 4; ++mt){
          int abm = mt*16 + id;
          h8 a = aload16(hsrc + ((size_t)abm << 10) + col);
          a0[mt] = __builtin_amdgcn_mfma_f32_16x16x32_f16(a, w0[l], a0[mt], 0,0,0);
          a1[mt] = __builtin_amdgcn_mfma_f32_16x16x32_f16(a, w1[l], a1[mt], 0,0,0);
        }
      }
      #pragma unroll
      for (int mt = 0; mt < 4; ++mt){
        *(f32x4*)&Gs[t & 1][wave][id][mt*16 + quad*4]      = a0[mt];
        *(f32x4*)&Gs[t & 1][wave][16 + id][mt*16 + quad*4] = a1[mt];
      }
      __syncthreads();     // the ONLY barrier this epoch
      ushort2 hb; float2 hf;
      #pragma unroll
      for (int jj = 0; jj < 2; ++jj){
        int jl = jq*2 + jj;
        float p[4];
        #pragma unroll
        for (int g = 0; g < 4; ++g){
          int e = (g >> 1)*16 + (g & 1)*8 + jl;
          p[g] = Gs[t & 1][0][e][cb] + Gs[t & 1][1][e][cb]
               + Gs[t & 1][2][e][cb] + Gs[t & 1][3][e][cb] + bs[g][jj];
        }
        float iv = sigm(p[0]), fv = sigm(p[1]), gv = tanh_f(p[2]), ov = sigm(p[3]);
        float c = fv*c2[jj] + iv*gv;
        c2[jj] = c;
        float h = ov * tanh_f(c);
        (&hf.x)[jj] = h;
        ((u16*)&hb)[jj] = f2h(h);
      }
      union { ushort2 s; unsigned int v; } pk; pk.s = hb;
      __hip_atomic_store((unsigned int*)&hout[(size_t)cb*HH + j0 + jq*2],
                         pk.v, __ATOMIC_RELAXED, __HIP_MEMORY_SCOPE_AGENT);
      if (t == TT - 1)
        *(float2*)&hfin[(size_t)(BB*HH) + (size_t)cb*HH + j0 + jq*2] = hf;
      // ---- wave-local drain + per-wave stamp (attests y0[t]/h1[t-1] reads done too) ----
      asm volatile("s_waitcnt vmcnt(0)" ::: "memory");
      if (lane == 0)
        __hip_atomic_store(stamp1 + jg*32 + wave, t + 1, __ATOMIC_RELAXED, __HIP_MEMORY_SCOPE_AGENT);
    }
  }
}

// ---------------- FC head ----------------
__global__ void fc_kernel(const float* __restrict__ hfin, const float* __restrict__ fcw,
                          const float* __restrict__ fcb, float* __restrict__ out){
  int row = blockIdx.x;          // 0..127  (0..63 layer0 hT, 64..127 layer1 hT)
  int lane = threadIdx.x;        // 64
  const float* h = hfin + (size_t)row*HH;
  float a0 = 0.f, a1 = 0.f;
  for (int j = lane; j < HH; j += 64){
    float v = h[j]; v = v > 0.f ? v : 0.f;
    a0 += v * fcw[j];
    a1 += v * fcw[HH + j];
  }
  for (int off = 32; off; off >>= 1){ a0 += __shfl_down(a0, off); a1 += __shfl_down(a1, off); }
  if (lane == 0){
    out[row*2 + 0] = 1.f/(1.f + __expf(-(a0 + fcb[0])));
    out[row*2 + 1] = 1.f/(1.f + __expf(-(a1 + fcb[1])));
  }
}

// ---------------- launch ----------------
extern "C" void kernel_launch(void* const* d_in, const int* in_sizes, int n_in,
                              void* d_out, int out_size, void* d_ws, size_t ws_size,
                              hipStream_t stream){
  (void)in_sizes; (void)n_in; (void)out_size; (void)ws_size;
  const float* x    = (const float*)d_in[0];
  const float* Wih0 = (const float*)d_in[1];
  const float* Whh0 = (const float*)d_in[2];
  const float* bih0 = (const float*)d_in[3];
  const float* bhh0 = (const float*)d_in[4];
  const float* Wih1 = (const float*)d_in[5];
  const float* Whh1 = (const float*)d_in[6];
  const float* bih1 = (const float*)d_in[7];
  const float* bhh1 = (const float*)d_in[8];
  const float* fcw  = (const float*)d_in[9];
  const float* fcb  = (const float*)d_in[10];

  char* w = (char*)d_ws;
  size_t off = 0;
  auto take = [&](size_t bytes)->char*{
    char* p = w + off; off += (bytes + 255) & ~(size_t)255; return p;
  };
  u16*   xb    = (u16*)  take((size_t)TT*BB*II*2);       // 16 MB
  u16*   wsw0  = (u16*)  take((size_t)G4*1280*2);        // 10 MB  (K=256+1024)
  u16*   wsw1  = (u16*)  take((size_t)G4*2048*2);        // 16 MB  (K=1024+1024)
  float* bias0 = (float*)take(G4*4);
  float* bias1 = (float*)take(G4*4);
  u16*   h0buf = (u16*)  take(8*(size_t)BB*HH*2);        // 1 MB ring (8 slots)
  u16*   h1buf = (u16*)  take(8*(size_t)BB*HH*2);
  float* hfin  = (float*)take(2*(size_t)BB*HH*4);        // 512 KB
  int*   stamp0= (int*)  take(128*128);                  // 128 quads x 128B
  int*   stamp1= (int*)  take(128*128);

  hipMemsetAsync(h0buf, 0, 8*(size_t)BB*HH*2, stream);
  hipMemsetAsync(h1buf, 0, 8*(size_t)BB*HH*2, stream);
  hipMemsetAsync(stamp0, 0, 128*128, stream);
  hipMemsetAsync(stamp1, 0, 128*128, stream);

  bias_comb_kernel<<<16, 256, 0, stream>>>(bih0, bhh0, bias0, G4);
  bias_comb_kernel<<<16, 256, 0, stream>>>(bih1, bhh1, bias1, G4);
  xconv_kernel<<<TT*BB, 64, 0, stream>>>(x, xb);
  wswz_kernel<<<2560, 256, 0, stream>>>(Wih0, II, Whh0, HH, wsw0, 40);
  wswz_kernel<<<4096, 256, 0, stream>>>(Wih1, HH, Whh1, HH, wsw1, 64);

  lstm_fused_kernel<<<256, 256, 0, stream>>>(xb, wsw0, wsw1, bias0, bias1,
                                             h0buf, h1buf, hfin, stamp0, stamp1);
  fc_kernel<<<2*BB, 64, 0, stream>>>(hfin, fcw, fcb, (float*)d_out);
}